// Round 3
// baseline (951.088 us; speedup 1.0000x reference)
//
#include <hip/hip_runtime.h>

#define B_SZ 16
#define L_SZ 2048
#define DIN 64
#define H_SZ 256
#define NH 32
#define NL 4
#define TC 128
#define NTC 16

typedef __attribute__((ext_vector_type(8))) __bf16 bf16x8;
typedef __attribute__((ext_vector_type(4))) float f32x4;

__device__ __forceinline__ unsigned short f2b(float f) {
  unsigned int u = __builtin_bit_cast(unsigned int, f);
  unsigned int r = u + 0x7fffu + ((u >> 16) & 1u);  // RNE (no NaN inputs here)
  return (unsigned short)(r >> 16);
}
__device__ __forceinline__ float b2f(unsigned short u) {
  unsigned int v = ((unsigned int)u) << 16;
  return __builtin_bit_cast(float, v);
}

// ---------------- encoder: h[b][hh][l] = x[b][l][:] @ enc_w[:,hh] + enc_b ----------------
__global__ void k_encoder(const float* __restrict__ x, const float* __restrict__ w,
                          const float* __restrict__ bias, float* __restrict__ hbuf) {
  __shared__ float wlds[DIN * H_SZ];  // 64 KB
  int tid = threadIdx.x;
  for (int i = tid; i < DIN * H_SZ; i += 256) wlds[i] = w[i];
  int blk = blockIdx.x;            // 512 blocks: b(16) x q(4) x ltile(8)
  int b = blk >> 5;
  int q = (blk >> 3) & 3;
  int l = ((blk & 7) << 8) + tid;
  float xr[DIN];
  const float4* xp = (const float4*)(x + (size_t)(b * L_SZ + l) * DIN);
#pragma unroll
  for (int d4 = 0; d4 < 16; ++d4) {
    float4 v = xp[d4];
    xr[d4 * 4 + 0] = v.x; xr[d4 * 4 + 1] = v.y; xr[d4 * 4 + 2] = v.z; xr[d4 * 4 + 3] = v.w;
  }
  __syncthreads();
  for (int i = 0; i < 64; ++i) {
    int hh = (q << 6) + i;
    float acc = bias[hh];
#pragma unroll
    for (int d = 0; d < DIN; ++d) acc = fmaf(xr[d], wlds[d * H_SZ + hh], acc);
    hbuf[(b * H_SZ + hh) * L_SZ + l] = acc;
  }
}

// ---------------- convert w_out to bf16 ----------------
__global__ void k_cvtw(const float* __restrict__ w, unsigned short* __restrict__ wbf, int n) {
  int i = blockIdx.x * 256 + threadIdx.x;
  if (i < n) wbf[i] = f2b(w[i]);
}

// ---------------- precompute per-state params + zero flags/counters ----------------
__global__ void k_params(const float* __restrict__ log_dt, const float* __restrict__ log_A_real,
                         const float* __restrict__ A_imag, const float* __restrict__ C_re,
                         const float* __restrict__ C_im, float* __restrict__ par,
                         int* __restrict__ flags, int* __restrict__ tctr) {
  int id = blockIdx.x * 256 + threadIdx.x;  // i*8192 + h*32 + n
  if (id < NL * B_SZ * NTC) flags[id] = 0;
  if (id < NL) tctr[id] = 0;
  if (id >= NL * H_SZ * NH) return;
  int i = id >> 13;
  int hn = id & 8191;
  int h = hn >> 5;
  float dt = expf(log_dt[i * H_SZ + h]);
  float Ar = -expf(log_A_real[(size_t)i * H_SZ * NH + hn]);
  float Ai = A_imag[(size_t)i * H_SZ * NH + hn];
  float dr = dt * Ar, di = dt * Ai;
  float e = expf(dr), sn, cs;
  sincosf(di, &sn, &cs);
  float lr = e * cs, li = e * sn;
  float eT = expf((float)TC * dr), snT, csT;
  sincosf((float)TC * di, &snT, &csT);
  float Cr = C_re[(size_t)i * H_SZ * NH + hn], Ci = C_im[(size_t)i * H_SZ * NH + hn];
  float wr = lr - 1.f, wi = li;
  float pr = Cr * wr - Ci * wi;
  float pi = Cr * wi + Ci * wr;
  float inv = 2.f / fmaf(Ar, Ar, Ai * Ai);
  float4* p = (float4*)(par + (size_t)id * 8);
  p[0] = make_float4(lr, li, (pr * Ar + pi * Ai) * inv, (pi * Ar - pr * Ai) * inv);
  p[1] = make_float4(eT * csT, eT * snT, 0.f, 0.f);
}

// ---------------- fused per-layer kernel with decoupled lookback ----------------
__launch_bounds__(1024, 4)
__global__ void k_layer(float* __restrict__ hbuf, float4* __restrict__ sFq,
                        const float* __restrict__ par,
                        const float* __restrict__ D_skip,
                        const unsigned short* __restrict__ wbf,
                        const float* __restrict__ b_out,
                        const float* __restrict__ ln_g, const float* __restrict__ ln_b,
                        int* __restrict__ flag, int* __restrict__ tctr,
                        float* __restrict__ pooledPart, int last) {
  __shared__ __align__(16) unsigned short yt[TC][H_SZ + 8];  // 67.6 KB
  __shared__ float part[TC][8][2];
  __shared__ float stats[TC][2];
  __shared__ int tileS;
  int tid = threadIdx.x;
  // dynamic tile grab (c-major) -> lookback deps always grabbed first
  if (tid == 0) tileS = atomicAdd(tctr, 1);
  __syncthreads();
  int tile = tileS;
  int c = tile >> 4;
  int b = tile & 15;
  int l0 = c * TC;

  int h = tid >> 2, ng = tid & 3;
  const float4* pp = (const float4*)(par + (size_t)(h * NH + ng * 8) * 8);
  float lr[8], li[8], sre[8], sim[8];
#pragma unroll
  for (int k = 0; k < 8; ++k) {
    float4 p0 = pp[k * 2];
    lr[k] = p0.x; li[k] = p0.y;
    sre[k] = 0.f; sim[k] = 0.f;
  }
  // ---- pass A: local chunk scan (state only) ----
  {
    const float* xp = hbuf + (b * H_SZ + h) * L_SZ + l0;
    float4 xv = *(const float4*)xp;
    for (int j4 = 0; j4 < TC; j4 += 4) {
      float4 xn = xv;
      if (j4 + 4 < TC) xn = *(const float4*)(xp + j4 + 4);
      float xe[4] = {xv.x, xv.y, xv.z, xv.w};
#pragma unroll
      for (int e = 0; e < 4; ++e) {
        float xj = xe[e];
#pragma unroll
        for (int k = 0; k < 8; ++k) {
          float nr = fmaf(lr[k], sre[k], xj);
          nr = fmaf(-li[k], sim[k], nr);
          float ni = lr[k] * sim[k];
          ni = fmaf(li[k], sre[k], ni);
          sre[k] = nr; sim[k] = ni;
        }
      }
      xv = xn;
    }
  }
  // ---- publish chunk-final state ----
  {
    float4* myF = sFq + (((size_t)((b << 4) + c) * H_SZ + h) * 4 + ng) * 4;
#pragma unroll
    for (int q = 0; q < 4; ++q)
      myF[q] = make_float4(sre[2 * q], sim[2 * q], sre[2 * q + 1], sim[2 * q + 1]);
    __syncthreads();
    if (tid == 0)
      __hip_atomic_store(&flag[(b << 4) + c], 1, __ATOMIC_RELEASE, __HIP_MEMORY_SCOPE_AGENT);
  }
  // ---- lookback: poll all predecessors, combine carries ----
  float cre[8], cim[8];
#pragma unroll
  for (int k = 0; k < 8; ++k) { cre[k] = 0.f; cim[k] = 0.f; }
  if (c > 0) {
    if (tid < c) {
      while (__hip_atomic_load(&flag[(b << 4) + tid], __ATOMIC_ACQUIRE,
                               __HIP_MEMORY_SCOPE_AGENT) == 0)
        __builtin_amdgcn_s_sleep(2);
    }
    __syncthreads();
    __threadfence();
    float lTr[8], lTi[8];
#pragma unroll
    for (int k = 0; k < 8; ++k) {
      float4 p1 = pp[k * 2 + 1];
      lTr[k] = p1.x; lTi[k] = p1.y;
    }
    for (int cc = 0; cc < c; ++cc) {
      const float4* fp = sFq + (((size_t)((b << 4) + cc) * H_SZ + h) * 4 + ng) * 4;
#pragma unroll
      for (int q = 0; q < 4; ++q) {
        float4 f = fp[q];
        const int k0 = 2 * q, k1 = 2 * q + 1;
        float nr0 = fmaf(lTr[k0], cre[k0], f.x); nr0 = fmaf(-lTi[k0], cim[k0], nr0);
        float ni0 = fmaf(lTr[k0], cim[k0], f.y); ni0 = fmaf(lTi[k0], cre[k0], ni0);
        cre[k0] = nr0; cim[k0] = ni0;
        float nr1 = fmaf(lTr[k1], cre[k1], f.z); nr1 = fmaf(-lTi[k1], cim[k1], nr1);
        float ni1 = fmaf(lTr[k1], cim[k1], f.w); ni1 = fmaf(lTi[k1], cre[k1], ni1);
        cre[k1] = nr1; cim[k1] = ni1;
      }
    }
  }
  // ---- prefetch residual column for phase 4 (overlaps pass B) ----
  int j = tid & 127, hg = tid >> 7;
  float vreg[32];
  {
    const float* xc = hbuf + (b * H_SZ + (hg << 5)) * L_SZ + l0 + j;
#pragma unroll
    for (int k = 0; k < 32; ++k) vreg[k] = xc[(size_t)k * L_SZ];
  }
  // ---- pass B: full recurrence from carry; y + D*x -> LDS (bf16) ----
  {
    float c2r[8], c2i[8];
#pragma unroll
    for (int k = 0; k < 8; ++k) {
      float4 p0 = pp[k * 2];
      c2r[k] = p0.z; c2i[k] = p0.w;
      sre[k] = cre[k]; sim[k] = cim[k];
    }
    float Dh = D_skip[h];
    const float* xp = hbuf + (b * H_SZ + h) * L_SZ + l0;
    float4 xv = *(const float4*)xp;
    for (int j4 = 0; j4 < TC; j4 += 4) {
      float4 xn = xv;
      if (j4 + 4 < TC) xn = *(const float4*)(xp + j4 + 4);
      float xe[4] = {xv.x, xv.y, xv.z, xv.w};
#pragma unroll
      for (int e = 0; e < 4; ++e) {
        float xj = xe[e];
        float yp0 = 0.f, yp1 = 0.f;
#pragma unroll
        for (int k = 0; k < 8; ++k) {
          float nr = fmaf(lr[k], sre[k], xj);
          nr = fmaf(-li[k], sim[k], nr);
          float ni = lr[k] * sim[k];
          ni = fmaf(li[k], sre[k], ni);
          sre[k] = nr; sim[k] = ni;
          if (k & 1) {
            yp1 = fmaf(c2r[k], nr, yp1);
            yp1 = fmaf(-c2i[k], ni, yp1);
          } else {
            yp0 = fmaf(c2r[k], nr, yp0);
            yp0 = fmaf(-c2i[k], ni, yp0);
          }
        }
        float yp = yp0 + yp1;
        yp += __shfl_xor(yp, 1);
        yp += __shfl_xor(yp, 2);
        if (ng == 0) yt[j4 + e][h] = f2b(fmaf(Dh, xj, yp));
      }
      xv = xn;
    }
  }
  __syncthreads();
  // ---- phase 2: exact GELU in place (packed pairs) ----
  for (int it = 0; it < 16; ++it) {
    int id = it * 1024 + tid;
    int jr = id >> 7, hp = id & 127;
    unsigned int u = *(unsigned int*)&yt[jr][hp * 2];
    float v0 = b2f((unsigned short)(u & 0xffff));
    float v1 = b2f((unsigned short)(u >> 16));
    v0 = 0.5f * v0 * (1.f + erff(v0 * 0.70710678118654752f));
    v1 = 0.5f * v1 * (1.f + erff(v1 * 0.70710678118654752f));
    *(unsigned int*)&yt[jr][hp * 2] = (unsigned int)f2b(v0) | ((unsigned int)f2b(v1) << 16);
  }
  __syncthreads();
  // ---- phase 3: 1x1 conv (512x256 @ 256x128) via MFMA + GLU; z -> LDS ----
  {
    int w = tid >> 6, lane = tid & 63;
    int lrow = lane & 15, lk8 = (lane >> 4) << 3;
    f32x4 accA[8], accG[8];
    f32x4 zed = {0.f, 0.f, 0.f, 0.f};
#pragma unroll
    for (int jt = 0; jt < 8; ++jt) { accA[jt] = zed; accG[jt] = zed; }
    const unsigned short* wA = wbf + ((w << 4) + lrow) * H_SZ;
    const unsigned short* wG = wA + 256 * H_SZ;
#pragma unroll
    for (int k0 = 0; k0 < H_SZ; k0 += 32) {
      bf16x8 a0 = *(const bf16x8*)(wA + k0 + lk8);
      bf16x8 a1 = *(const bf16x8*)(wG + k0 + lk8);
#pragma unroll
      for (int jt = 0; jt < 8; ++jt) {
        bf16x8 bb = *(const bf16x8*)(&yt[(jt << 4) + lrow][k0 + lk8]);
        accA[jt] = __builtin_amdgcn_mfma_f32_16x16x32_bf16(a0, bb, accA[jt], 0, 0, 0);
        accG[jt] = __builtin_amdgcn_mfma_f32_16x16x32_bf16(a1, bb, accG[jt], 0, 0, 0);
      }
    }
    __syncthreads();  // all y reads done before overwrite with z
    int rbase = (lane >> 4) << 2;
    float bA[4], bG[4];
#pragma unroll
    for (int r = 0; r < 4; ++r) {
      bA[r] = b_out[(w << 4) + rbase + r];
      bG[r] = b_out[256 + (w << 4) + rbase + r];
    }
#pragma unroll
    for (int jt = 0; jt < 8; ++jt) {
#pragma unroll
      for (int r = 0; r < 4; ++r) {
        float a = accA[jt][r] + bA[r];
        float g = accG[jt][r] + bG[r];
        float z = a / (1.f + expf(-g));
        yt[(jt << 4) + lrow][(w << 4) + rbase + r] = f2b(z);
      }
    }
  }
  __syncthreads();
  // ---- phase 4: LN stats over H; v = z + prefetched residual ----
  {
    float s = 0.f, sq = 0.f;
#pragma unroll
    for (int k = 0; k < 32; ++k) {
      float v = b2f(yt[j][(hg << 5) + k]) + vreg[k];
      vreg[k] = v;
      s += v; sq = fmaf(v, v, sq);
    }
    part[j][hg][0] = s; part[j][hg][1] = sq;
  }
  __syncthreads();
  if (tid < TC) {
    float s = 0.f, sq = 0.f;
#pragma unroll
    for (int g8 = 0; g8 < 8; ++g8) { s += part[tid][g8][0]; sq += part[tid][g8][1]; }
    float mu = s * (1.f / 256.f);
    float var = sq * (1.f / 256.f) - mu * mu;
    stats[tid][0] = mu;
    stats[tid][1] = rsqrtf(var + 1e-5f);
  }
  __syncthreads();
  // ---- phase 5: normalized residual; write hbuf OR pool partials (last) ----
  {
    float mu = stats[j][0], rs = stats[j][1];
    if (!last) {
      float* xo = hbuf + (b * H_SZ + (hg << 5)) * L_SZ + l0 + j;
#pragma unroll
      for (int k = 0; k < 32; ++k) {
        int hh = (hg << 5) + k;
        xo[(size_t)k * L_SZ] = (vreg[k] - mu) * rs * ln_g[hh] + ln_b[hh];
      }
    } else {
#pragma unroll
      for (int k = 0; k < 32; ++k) {
        int hh = (hg << 5) + k;
        yt[j][hh] = f2b((vreg[k] - mu) * rs * ln_g[hh] + ln_b[hh]);
      }
      __syncthreads();
      if (tid < H_SZ) {
        float s = 0.f;
        for (int jj = 0; jj < TC; ++jj) s += b2f(yt[jj][tid]);
        pooledPart[(((b << 4) + c) << 8) + tid] = s;
      }
    }
  }
}

// ---------------- decoder MLP (single block) with pooling preamble ----------------
__global__ void k_decoder(const float* __restrict__ pooledPart,
                          const float* __restrict__ w1, const float* __restrict__ b1,
                          const float* __restrict__ w2, const float* __restrict__ b2,
                          const float* __restrict__ w3, const float* __restrict__ b3,
                          float* __restrict__ out) {
  __shared__ float P[16 * 256];
  __shared__ float O1[16 * 128];
  __shared__ float O2[16 * 64];
  int tid = threadIdx.x;
  for (int id = tid; id < 16 * 256; id += 256) {
    int b = id >> 8, hh = id & 255;
    float s = 0.f;
#pragma unroll
    for (int cpart = 0; cpart < 16; ++cpart)
      s += pooledPart[(((b << 4) + cpart) << 8) + hh];
    P[id] = s * (1.f / 2048.f);
  }
  __syncthreads();
  for (int id = tid; id < 16 * 128; id += 256) {
    int r = id >> 7, cc = id & 127;
    float acc = b1[cc];
    for (int d = 0; d < 256; ++d) acc = fmaf(P[(r << 8) + d], w1[(d << 7) + cc], acc);
    O1[id] = fmaxf(acc, 0.f);
  }
  __syncthreads();
  for (int id = tid; id < 16 * 64; id += 256) {
    int r = id >> 6, cc = id & 63;
    float acc = b2[cc];
    for (int d = 0; d < 128; ++d) acc = fmaf(O1[(r << 7) + d], w2[(d << 6) + cc], acc);
    O2[id] = fmaxf(acc, 0.f);
  }
  __syncthreads();
  for (int id = tid; id < 16 * 32; id += 256) {
    int r = id >> 5, cc = id & 31;
    float acc = b3[cc];
    for (int d = 0; d < 64; ++d) acc = fmaf(O2[(r << 6) + d], w3[(d << 5) + cc], acc);
    out[id] = acc;
  }
}

extern "C" void kernel_launch(void* const* d_in, const int* in_sizes, int n_in,
                              void* d_out, int out_size, void* d_ws, size_t ws_size,
                              hipStream_t stream) {
  const float* x          = (const float*)d_in[0];
  const float* enc_w      = (const float*)d_in[1];
  const float* enc_b      = (const float*)d_in[2];
  const float* log_dt     = (const float*)d_in[3];
  const float* C_re       = (const float*)d_in[4];
  const float* C_im       = (const float*)d_in[5];
  const float* log_A_real = (const float*)d_in[6];
  const float* A_imag     = (const float*)d_in[7];
  const float* D_skip     = (const float*)d_in[8];
  const float* w_out      = (const float*)d_in[9];
  const float* b_out      = (const float*)d_in[10];
  const float* ln_g       = (const float*)d_in[11];
  const float* ln_b       = (const float*)d_in[12];
  const float* dw1        = (const float*)d_in[13];
  const float* db1        = (const float*)d_in[14];
  const float* dw2        = (const float*)d_in[15];
  const float* db2        = (const float*)d_in[16];
  const float* dw3        = (const float*)d_in[17];
  const float* db3        = (const float*)d_in[18];

  char* ws = (char*)d_ws;
  float* hbuf = (float*)ws;                                  // 33,554,432 B
  float4* sFq = (float4*)(ws + 33554432);                    // 16,777,216 B
  unsigned short* wbf = (unsigned short*)(ws + 50331648);    //  1,048,576 B
  float* par = (float*)(ws + 51380224);                      //  1,048,576 B
  float* pooledPart = (float*)(ws + 52428800);               //    262,144 B
  int* flags = (int*)(ws + 52690944);                        //      4,096 B
  int* tctr = (int*)(ws + 52695040);                         //         16 B

  k_encoder<<<512, 256, 0, stream>>>(x, enc_w, enc_b, hbuf);
  k_cvtw<<<2048, 256, 0, stream>>>(w_out, wbf, NL * 512 * H_SZ);
  k_params<<<128, 256, 0, stream>>>(log_dt, log_A_real, A_imag, C_re, C_im, par, flags, tctr);
  for (int i = 0; i < NL; ++i) {
    k_layer<<<256, 1024, 0, stream>>>(hbuf, sFq, par + (size_t)i * H_SZ * NH * 8,
                                      D_skip + i * H_SZ, wbf + i * 512 * H_SZ,
                                      b_out + i * 512, ln_g + i * H_SZ, ln_b + i * H_SZ,
                                      flags + i * B_SZ * NTC, tctr + i, pooledPart,
                                      (i == NL - 1) ? 1 : 0);
  }
  k_decoder<<<1, 256, 0, stream>>>(pooledPart, dw1, db1, dw2, db2, dw3, db3, (float*)d_out);
}